// Round 7
// baseline (143.652 us; speedup 1.0000x reference)
//
#include <hip/hip_runtime.h>
#include <hip/hip_bf16.h>

// ---------- problem sizes (fixed by setup_inputs) ----------
#define BB 8
#define SS 4096
#define NN 256      // d_state = d_input = d_output
#define CHUNK 32
#define NCH (SS/CHUNK)  // 128 chunks per batch

// ---------- ws layout (bytes) ----------
#define WS_FINU_B ((size_t)0)                        // 1 MiB u64 (hr pairs)
#define WS_FINV_B ((size_t)1 << 20)                  // 1 MiB u64 (hi pairs)
#define WS_FLAG_B ((size_t)2 << 20)                  // 2 KiB int flags (512)
#define WS_CP_B   (((size_t)2 << 20) + 65536)        // Cpack 256 KB
#define WS_BP_B   (((size_t)2 << 20) + 65536 + 262144) // Bpack 128 KB

typedef __bf16 bf16_t;
typedef bf16_t bf16x8 __attribute__((ext_vector_type(8)));
typedef float  f32x4  __attribute__((ext_vector_type(4)));
typedef unsigned int u32x4 __attribute__((ext_vector_type(4)));
typedef unsigned long long u64_t;

__device__ inline bf16_t f2b(float f) {
    __hip_bfloat16 h = __float2bfloat16(f);
    return __builtin_bit_cast(bf16_t, h);
}
__device__ inline float b2f_lo(unsigned v) {
    unsigned u = v << 16; return __builtin_bit_cast(float, u);
}
__device__ inline float b2f_hi(unsigned v) {
    unsigned u = v & 0xffff0000u; return __builtin_bit_cast(float, u);
}
__device__ inline unsigned pack2(float lo, float hi) {
    unsigned a = (unsigned)__builtin_bit_cast(unsigned short, f2b(lo));
    unsigned b = (unsigned)__builtin_bit_cast(unsigned short, f2b(hi));
    return a | (b << 16);
}
__device__ inline bf16x8 cvt8(f32x4 a, f32x4 b) {
    bf16x8 o;
    o[0]=f2b(a[0]); o[1]=f2b(a[1]); o[2]=f2b(a[2]); o[3]=f2b(a[3]);
    o[4]=f2b(b[0]); o[5]=f2b(b[1]); o[6]=f2b(b[2]); o[7]=f2b(b[3]);
    return o;
}

// bilinear-discretization constants for state n (verified)
__device__ inline void ssm_consts(const float* llr, const float* li, const float* ldt,
                                  int n, float& Ar, float& Ai, float& sr, float& si) {
    float lr = -expf(llr[n]);
    float im = li[n];
    float dt = expf(ldt[n]);
    dt = fminf(fmaxf(dt, 0.005f), 0.1f);
    float hr = 0.5f * dt * lr, hi = 0.5f * dt * im;
    float dr = 1.f - hr, di = -hi;
    float inv = 1.f / (dr*dr + di*di);
    Ar = ((1.f + hr)*dr + hi*di) * inv;
    Ai = (hi*dr - (1.f + hr)*di) * inv;
    sr = dt * dr * inv;
    si = -dt * di * inv;
}

// ============================================================
// kprep: pack C (virtual K=512, [Cr | -Ci]) and B (K=256) into bf16
// MFMA fragment order (verified): frag[(ks*16+ot)*64+lane] elem[e] =
//   src[(ot*16 + (lane&15))*256 + (ks&7)*32 + (lane>>4)*8 + e].
// bid 0..15 -> Cpack, 16..23 -> Bpack. bid 0 also clears the 512 flags
// (workspace is re-poisoned each iteration; flags MUST be zeroed).
// ============================================================
__global__ __launch_bounds__(256) void kprep(const float* __restrict__ Bw,
                                             const float* __restrict__ Cr,
                                             const float* __restrict__ Ci,
                                             u32x4* __restrict__ Cpack,
                                             u32x4* __restrict__ Bpack,
                                             int* __restrict__ flags) {
    int t = threadIdx.x, bid = blockIdx.x;
    if (bid == 0) {
        __hip_atomic_store(flags + t, 0, __ATOMIC_RELAXED, __HIP_MEMORY_SCOPE_AGENT);
        __hip_atomic_store(flags + t + 256, 0, __ATOMIC_RELAXED, __HIP_MEMORY_SCOPE_AGENT);
    }
    const float* src;
    float sign;
    u32x4* dst;
    int ks;
    if (bid < 16) { ks = bid;      src = (ks < 8) ? Cr : Ci; sign = (ks < 8) ? 1.f : -1.f; dst = Cpack; }
    else          { ks = bid - 16; src = Bw;                 sign = 1.f;                   dst = Bpack; }
    int ksl = ks & 7;
    #pragma unroll
    for (int jj = 0; jj < 4; ++jj) {
        int s = t + 256 * jj;
        int ot = s >> 6, lane = s & 63;
        int o  = ot*16 + (lane & 15);
        int kb = ksl*32 + (lane >> 4)*8;
        bf16x8 v;
        #pragma unroll
        for (int e = 0; e < 8; ++e) v[e] = f2b(sign * src[o*256 + kb + e]);
        dst[(ks*16 + ot)*64 + lane] = __builtin_bit_cast(u32x4, v);
    }
}

// Unified LDS addressing (hr at 0, hi at +32768):
//   byte(m, n) = m*512 + (((n>>3) ^ ((m>>1)&31)) << 4) + (n&7)*2
// X staging aliases the hi half (dead until the scan writes hi):
//   byte(m, k) = 32768 + m*128 + (((k>>3) ^ (m&7)) << 4) + (k&7)*2

// ============================================================
// kfused (512 blocks x 256 thr, 2/CU => full co-residency):
//  ph1: V^T = Bpack @ X^T (swapped MFMA operands -> b64 epilogue)
//  ph2: chunk-local complex scan in LDS; finals -> ws (relaxed agent
//       sc1 write-through atomics), then per-block RELEASE flag
//  ph3: decoupled lookback: RELAXED polls (no per-poll invalidate),
//       ONE acquire fence (buffer_inv), then PLAIN COALESCED u64 loads
//       of finals (atomics don't coalesce -- that was Round-5's stall),
//       carry prefix + G-add in LDS
//  ph4: out = [hr|hi] @ Cpack^T (K=512)
// Deadlock-safe: waits only on smaller block IDs + all 512 blocks
// co-resident (2/CU x 256 CU, 64 KB LDS each).
// ============================================================
__global__ __launch_bounds__(256, 2) void kfused(
    const float* __restrict__ X,
    const float* __restrict__ llr,
    const float* __restrict__ li,
    const float* __restrict__ ldt,
    const u32x4* __restrict__ Bpack,
    const u32x4* __restrict__ Cpack,
    u64_t* __restrict__ finu,
    u64_t* __restrict__ finv,
    int* __restrict__ flags,
    float* __restrict__ out)
{
    __shared__ __align__(16) char hlds[65536];
    int t = threadIdx.x;
    int bid = blockIdx.x;
    int m0 = bid * 64;
    int b = bid >> 6;               // batch
    int d = bid & 63;               // block index within batch
    int cbase = d * 2;              // first chunk index of this block
    int w = t >> 6, lane = t & 63, q = lane >> 4, r = lane & 15;

    // ---------------- phase 1: V^T = Bw @ X^T ----------------
    f32x4 acc[4][4] = {};   // [nt][mt]: D rows = states, cols = m rows
    for (int kk = 0; kk < 4; ++kk) {
        #pragma unroll
        for (int ss = 0; ss < 2; ++ss) {
            int s = t + 256 * ss;
            int m = s >> 3, kg = s & 7;
            const f32x4* px = (const f32x4*)(X + (size_t)(m0 + m)*256 + kk*64 + kg*8);
            *(bf16x8*)(hlds + 32768 + m*128 + ((kg ^ (m & 7)) << 4)) = cvt8(px[0], px[1]);
        }
        __syncthreads();
        bf16x8 bp[2][4], xf[2][4];
        #pragma unroll
        for (int kb = 0; kb < 2; ++kb) {
            #pragma unroll
            for (int nt = 0; nt < 4; ++nt)
                bp[kb][nt] = __builtin_bit_cast(bf16x8,
                    Bpack[((kk*2 + kb)*16 + w*4 + nt)*64 + lane]);
            #pragma unroll
            for (int mt = 0; mt < 4; ++mt) {
                int m = mt*16 + r;
                xf[kb][mt] = *(const bf16x8*)(hlds + 32768 + m*128 +
                                              (((kb*4 + q) ^ (m & 7)) << 4));
            }
        }
        #pragma unroll
        for (int kb = 0; kb < 2; ++kb)
            #pragma unroll
            for (int nt = 0; nt < 4; ++nt)
                #pragma unroll
                for (int mt = 0; mt < 4; ++mt)
                    acc[nt][mt] = __builtin_amdgcn_mfma_f32_16x16x32_bf16(
                        bp[kb][nt], xf[kb][mt], acc[nt][mt], 0, 0, 0);
        __syncthreads();
    }
    // epilogue: lane holds 4 consecutive states (regs) -> one b64 per (nt,mt)
    #pragma unroll
    for (int nt = 0; nt < 4; ++nt) {
        int n0 = w*64 + nt*16 + q*4;
        #pragma unroll
        for (int mt = 0; mt < 4; ++mt) {
            int m = mt*16 + r;
            uint2 dd;
            dd.x = pack2(acc[nt][mt][0], acc[nt][mt][1]);
            dd.y = pack2(acc[nt][mt][2], acc[nt][mt][3]);
            *(uint2*)(hlds + m*512 + (((n0 >> 3) ^ ((m >> 1) & 31)) << 4) + (n0 & 7)*2) = dd;
        }
    }
    __syncthreads();

    // ---------------- phase 2: chunk-local scan ----------------
    int p = t & 127, ch = t >> 7;   // thread: states 2p,2p+1 ; chunk ch
    int cb = cbase + ch;
    float Ar0,Ai0,sr0,si0, Ar1,Ai1,sr1,si1;
    ssm_consts(llr, li, ldt, 2*p,   Ar0, Ai0, sr0, si0);
    ssm_consts(llr, li, ldt, 2*p+1, Ar1, Ai1, sr1, si1);
    {
        float hr0=0.f, hi0=0.f, hr1=0.f, hi1=0.f;
        #pragma unroll
        for (int i2 = 0; i2 < 16; ++i2) {
            int row = ch*32 + i2*2;
            char* a = hlds + row*512 + (((p >> 2) ^ ((row >> 1) & 31)) << 4) + (p & 3)*4;
            unsigned v0 = *(unsigned*)a;
            unsigned v1 = *(unsigned*)(a + 512);
            float x0 = b2f_lo(v0), x1 = b2f_hi(v0);
            float t0r = fmaf(Ar0, hr0, fmaf(-Ai0, hi0, sr0*x0));
            float t0i = fmaf(Ar0, hi0, fmaf( Ai0, hr0, si0*x0));
            float t1r = fmaf(Ar1, hr1, fmaf(-Ai1, hi1, sr1*x1));
            float t1i = fmaf(Ar1, hi1, fmaf( Ai1, hr1, si1*x1));
            hr0=t0r; hi0=t0i; hr1=t1r; hi1=t1i;
            *(unsigned*)a           = pack2(hr0, hr1);
            *(unsigned*)(a + 32768) = pack2(hi0, hi1);
            x0 = b2f_lo(v1); x1 = b2f_hi(v1);
            t0r = fmaf(Ar0, hr0, fmaf(-Ai0, hi0, sr0*x0));
            t0i = fmaf(Ar0, hi0, fmaf( Ai0, hr0, si0*x0));
            t1r = fmaf(Ar1, hr1, fmaf(-Ai1, hi1, sr1*x1));
            t1i = fmaf(Ar1, hi1, fmaf( Ai1, hr1, si1*x1));
            hr0=t0r; hi0=t0i; hr1=t1r; hi1=t1i;
            *(unsigned*)(a + 512)         = pack2(hr0, hr1);
            *(unsigned*)(a + 32768 + 512) = pack2(hi0, hi1);
        }
        // finals -> ws via relaxed agent-scope u64 atomics (write-through
        // to MALL so the release flag makes them agent-visible)
        float2 fr2; fr2.x = hr0; fr2.y = hr1;
        float2 fi2; fi2.x = hi0; fi2.y = hi1;
        size_t fidx = (size_t)(b*NCH + cb)*128 + p;
        __hip_atomic_store(finu + fidx, __builtin_bit_cast(u64_t, fr2),
                           __ATOMIC_RELAXED, __HIP_MEMORY_SCOPE_AGENT);
        __hip_atomic_store(finv + fidx, __builtin_bit_cast(u64_t, fi2),
                           __ATOMIC_RELAXED, __HIP_MEMORY_SCOPE_AGENT);
    }
    __syncthreads();   // drains vmcnt per wave -> all finals complete
    if (t == 0)
        __hip_atomic_store(flags + bid, 1, __ATOMIC_RELEASE, __HIP_MEMORY_SCOPE_AGENT);

    // ---------------- phase 3: lookback + G-add ----------------
    if (cb > 0) {
        // parallel wait: lanes 0..d-1 each watch one predecessor flag.
        // RELAXED polls + ONE acquire fence (single buffer_inv per wave).
        if (d > 0) {
            int fi_ = b*64 + ((lane < d) ? lane : 0);
            while (true) {
                int fl = __hip_atomic_load(flags + fi_, __ATOMIC_RELAXED,
                                           __HIP_MEMORY_SCOPE_AGENT);
                if (__all(fl != 0)) break;
                __builtin_amdgcn_s_sleep(4);
            }
            __builtin_amdgcn_fence(__ATOMIC_ACQUIRE, "agent");
        }
        float P0r=Ar0, P0i=Ai0, P1r=Ar1, P1i=Ai1;   // -> A^32
        #pragma unroll
        for (int i = 0; i < 5; ++i) {
            float u0 = P0r*P0r - P0i*P0i; P0i = 2.f*P0r*P0i; P0r = u0;
            float u1 = P1r*P1r - P1i*P1i; P1i = 2.f*P1r*P1i; P1r = u1;
        }
        float c0r=0.f, c0i=0.f, c1r=0.f, c1i=0.f;
        // PLAIN coalesced u64 loads (atomics don't coalesce; the fence
        // above already synchronized -- L2 was invalidated, lines refill
        // from MALL). Wave reads 512 B contiguous per row.
        #pragma unroll 4
        for (int j = 0; j < cb; ++j) {
            u64_t vr = finu[(size_t)(b*NCH + j)*128 + p];
            u64_t vi = finv[(size_t)(b*NCH + j)*128 + p];
            float2 fr = __builtin_bit_cast(float2, vr);
            float2 fi = __builtin_bit_cast(float2, vi);
            float n0r = fmaf(P0r, c0r, fmaf(-P0i, c0i, fr.x));
            float n0i = fmaf(P0r, c0i, fmaf( P0i, c0r, fi.x));
            float n1r = fmaf(P1r, c1r, fmaf(-P1i, c1i, fr.y));
            float n1i = fmaf(P1r, c1i, fmaf( P1i, c1r, fi.y));
            c0r=n0r; c0i=n0i; c1r=n1r; c1i=n1i;
        }
        float g0r = Ar0*c0r - Ai0*c0i, g0i = Ar0*c0i + Ai0*c0r;
        float g1r = Ar1*c1r - Ai1*c1i, g1i = Ar1*c1i + Ai1*c1r;
        #pragma unroll
        for (int i2 = 0; i2 < 16; ++i2) {
            int row = ch*32 + i2*2;
            char* a = hlds + row*512 + (((p >> 2) ^ ((row >> 1) & 31)) << 4) + (p & 3)*4;
            unsigned ur0 = *(unsigned*)a;
            unsigned ur1 = *(unsigned*)(a + 512);
            unsigned ui0 = *(unsigned*)(a + 32768);
            unsigned ui1 = *(unsigned*)(a + 32768 + 512);
            *(unsigned*)a           = pack2(b2f_lo(ur0) + g0r, b2f_hi(ur0) + g1r);
            *(unsigned*)(a + 32768) = pack2(b2f_lo(ui0) + g0i, b2f_hi(ui0) + g1i);
            { float t0 = Ar0*g0r - Ai0*g0i; g0i = fmaf(Ar0, g0i, Ai0*g0r); g0r = t0;
              float t1 = Ar1*g1r - Ai1*g1i; g1i = fmaf(Ar1, g1i, Ai1*g1r); g1r = t1; }
            *(unsigned*)(a + 512)         = pack2(b2f_lo(ur1) + g0r, b2f_hi(ur1) + g1r);
            *(unsigned*)(a + 32768 + 512) = pack2(b2f_lo(ui1) + g0i, b2f_hi(ui1) + g1i);
            { float t0 = Ar0*g0r - Ai0*g0i; g0i = fmaf(Ar0, g0i, Ai0*g0r); g0r = t0;
              float t1 = Ar1*g1r - Ai1*g1i; g1i = fmaf(Ar1, g1i, Ai1*g1r); g1r = t1; }
        }
    }
    __syncthreads();

    // ---------------- phase 4: out = [hr|hi] @ Cpack^T (K=512) ----------------
    f32x4 acc2[4][4] = {};  // [mt][nt]
    #pragma unroll
    for (int ks = 0; ks < 16; ++ks) {
        int base = (ks & 8) ? 32768 : 0;
        int kin = ks & 7;
        bf16x8 af[4];
        #pragma unroll
        for (int mt = 0; mt < 4; ++mt) {
            int row = mt*16 + r;
            af[mt] = *(const bf16x8*)(hlds + base + row*512 +
                     (((kin*4 + q) ^ ((row >> 1) & 31)) << 4));
        }
        #pragma unroll
        for (int nt = 0; nt < 4; ++nt) {
            bf16x8 cf = __builtin_bit_cast(bf16x8, Cpack[(ks*16 + w*4 + nt)*64 + lane]);
            #pragma unroll
            for (int mt = 0; mt < 4; ++mt)
                acc2[mt][nt] = __builtin_amdgcn_mfma_f32_16x16x32_bf16(
                    af[mt], cf, acc2[mt][nt], 0, 0, 0);
        }
    }
    #pragma unroll
    for (int mt = 0; mt < 4; ++mt)
        #pragma unroll
        for (int nt = 0; nt < 4; ++nt)
            #pragma unroll
            for (int reg = 0; reg < 4; ++reg)
                out[(size_t)(m0 + mt*16 + q*4 + reg)*NN + w*64 + nt*16 + r] =
                    acc2[mt][nt][reg];
}

extern "C" void kernel_launch(void* const* d_in, const int* in_sizes, int n_in,
                              void* d_out, int out_size, void* d_ws, size_t ws_size,
                              hipStream_t stream) {
    const float* x   = (const float*)d_in[0];
    const float* llr = (const float*)d_in[1];
    const float* li  = (const float*)d_in[2];
    const float* ldt = (const float*)d_in[3];
    const float* Bw  = (const float*)d_in[4];
    const float* Cr  = (const float*)d_in[5];
    const float* Ci  = (const float*)d_in[6];

    char* wsb = (char*)d_ws;
    u64_t* finu  = (u64_t*)(wsb + WS_FINU_B);
    u64_t* finv  = (u64_t*)(wsb + WS_FINV_B);
    int*   flags = (int*)(wsb + WS_FLAG_B);
    u32x4* Cpack = (u32x4*)(wsb + WS_CP_B);
    u32x4* Bpack = (u32x4*)(wsb + WS_BP_B);
    float* outp  = (float*)d_out;

    kprep<<<24, 256, 0, stream>>>(Bw, Cr, Ci, Cpack, Bpack, flags);
    kfused<<<512, 256, 0, stream>>>(x, llr, li, ldt, Bpack, Cpack,
                                    finu, finv, flags, outp);
}

// Round 8
// 127.905 us; speedup vs baseline: 1.1231x; 1.1231x over previous
//
#include <hip/hip_runtime.h>
#include <hip/hip_bf16.h>

// ---------- problem sizes (fixed by setup_inputs) ----------
#define BB 8
#define SS 4096
#define NN 256      // d_state = d_input = d_output
#define CHUNK 32
#define NCH (SS/CHUNK)  // 128 chunks per batch

// ---------- ws layout (bytes) ----------
#define WS_FINU_B ((size_t)0)                        // 1 MiB u64 (hr pairs)
#define WS_FINV_B ((size_t)1 << 20)                  // 1 MiB u64 (hi pairs)
#define WS_FLAG_B ((size_t)2 << 20)                  // 2 KiB int flags (512)
#define WS_CP_B   (((size_t)2 << 20) + 65536)        // Cpack 256 KB
#define WS_BP_B   (((size_t)2 << 20) + 65536 + 262144) // Bpack 128 KB

typedef __bf16 bf16_t;
typedef bf16_t bf16x8 __attribute__((ext_vector_type(8)));
typedef float  f32x4  __attribute__((ext_vector_type(4)));
typedef unsigned int u32x4 __attribute__((ext_vector_type(4)));
typedef unsigned long long u64_t;

__device__ inline bf16_t f2b(float f) {
    __hip_bfloat16 h = __float2bfloat16(f);
    return __builtin_bit_cast(bf16_t, h);
}
__device__ inline float b2f_lo(unsigned v) {
    unsigned u = v << 16; return __builtin_bit_cast(float, u);
}
__device__ inline float b2f_hi(unsigned v) {
    unsigned u = v & 0xffff0000u; return __builtin_bit_cast(float, u);
}
__device__ inline unsigned pack2(float lo, float hi) {
    unsigned a = (unsigned)__builtin_bit_cast(unsigned short, f2b(lo));
    unsigned b = (unsigned)__builtin_bit_cast(unsigned short, f2b(hi));
    return a | (b << 16);
}
__device__ inline bf16x8 cvt8(f32x4 a, f32x4 b) {
    bf16x8 o;
    o[0]=f2b(a[0]); o[1]=f2b(a[1]); o[2]=f2b(a[2]); o[3]=f2b(a[3]);
    o[4]=f2b(b[0]); o[5]=f2b(b[1]); o[6]=f2b(b[2]); o[7]=f2b(b[3]);
    return o;
}

// bilinear-discretization constants for state n (verified)
__device__ inline void ssm_consts(const float* llr, const float* li, const float* ldt,
                                  int n, float& Ar, float& Ai, float& sr, float& si) {
    float lr = -expf(llr[n]);
    float im = li[n];
    float dt = expf(ldt[n]);
    dt = fminf(fmaxf(dt, 0.005f), 0.1f);
    float hr = 0.5f * dt * lr, hi = 0.5f * dt * im;
    float dr = 1.f - hr, di = -hi;
    float inv = 1.f / (dr*dr + di*di);
    Ar = ((1.f + hr)*dr + hi*di) * inv;
    Ai = (hi*dr - (1.f + hr)*di) * inv;
    sr = dt * dr * inv;
    si = -dt * di * inv;
}

// ============================================================
// kprep: pack C (virtual K=512, [Cr | -Ci]) and B (K=256) into bf16
// MFMA fragment order (verified). bid 0..15 -> Cpack, 16..23 -> Bpack.
// bid 0 also clears the 512 flags (ws is re-poisoned every iteration).
// ============================================================
__global__ __launch_bounds__(256) void kprep(const float* __restrict__ Bw,
                                             const float* __restrict__ Cr,
                                             const float* __restrict__ Ci,
                                             u32x4* __restrict__ Cpack,
                                             u32x4* __restrict__ Bpack,
                                             int* __restrict__ flags) {
    int t = threadIdx.x, bid = blockIdx.x;
    if (bid == 0) {
        __hip_atomic_store(flags + t, 0, __ATOMIC_RELAXED, __HIP_MEMORY_SCOPE_AGENT);
        __hip_atomic_store(flags + t + 256, 0, __ATOMIC_RELAXED, __HIP_MEMORY_SCOPE_AGENT);
    }
    const float* src;
    float sign;
    u32x4* dst;
    int ks;
    if (bid < 16) { ks = bid;      src = (ks < 8) ? Cr : Ci; sign = (ks < 8) ? 1.f : -1.f; dst = Cpack; }
    else          { ks = bid - 16; src = Bw;                 sign = 1.f;                   dst = Bpack; }
    int ksl = ks & 7;
    #pragma unroll
    for (int jj = 0; jj < 4; ++jj) {
        int s = t + 256 * jj;
        int ot = s >> 6, lane = s & 63;
        int o  = ot*16 + (lane & 15);
        int kb = ksl*32 + (lane >> 4)*8;
        bf16x8 v;
        #pragma unroll
        for (int e = 0; e < 8; ++e) v[e] = f2b(sign * src[o*256 + kb + e]);
        dst[(ks*16 + ot)*64 + lane] = __builtin_bit_cast(u32x4, v);
    }
}

// Unified LDS addressing (hr at 0, hi at +32768):
//   byte(m, n) = m*512 + (((n>>3) ^ ((m>>1)&31)) << 4) + (n&7)*2
// X staging aliases the hi half:
//   byte(m, k) = 32768 + m*128 + (((k>>3) ^ (m&7)) << 4) + (k&7)*2

// ============================================================
// kfused (512 blocks x 256 thr, 2/CU => full co-residency):
//  ph1: V^T = Bpack @ X^T (swapped MFMA operands -> b64 epilogue)
//  ph2: chunk-local complex scan in LDS; finals -> ws (relaxed agent
//       write-through atomics), barrier, RELAXED per-block flag
//  ph3: WAVE-0-ONLY relaxed poll of <=63 predecessor flags, ONE
//       acquire fence per block (not per wave!), barrier, then plain
//       coalesced lookback + carry prefix + G-add in LDS
//  ph4: out = [hr|hi] @ Cpack^T (K=512)
// Deadlock-safe: waits only on smaller block IDs + all 512 blocks
// co-resident (2/CU x 256 CU, 64 KB LDS each).
// ============================================================
__global__ __launch_bounds__(256, 2) void kfused(
    const float* __restrict__ X,
    const float* __restrict__ llr,
    const float* __restrict__ li,
    const float* __restrict__ ldt,
    const u32x4* __restrict__ Bpack,
    const u32x4* __restrict__ Cpack,
    u64_t* __restrict__ finu,
    u64_t* __restrict__ finv,
    int* __restrict__ flags,
    float* __restrict__ out)
{
    __shared__ __align__(16) char hlds[65536];
    int t = threadIdx.x;
    int bid = blockIdx.x;
    int m0 = bid * 64;
    int b = bid >> 6;               // batch
    int d = bid & 63;               // block index within batch
    int cbase = d * 2;              // first chunk index of this block
    int w = t >> 6, lane = t & 63, q = lane >> 4, r = lane & 15;

    // ---------------- phase 1: V^T = Bw @ X^T ----------------
    f32x4 acc[4][4] = {};   // [nt][mt]: D rows = states, cols = m rows
    for (int kk = 0; kk < 4; ++kk) {
        #pragma unroll
        for (int ss = 0; ss < 2; ++ss) {
            int s = t + 256 * ss;
            int m = s >> 3, kg = s & 7;
            const f32x4* px = (const f32x4*)(X + (size_t)(m0 + m)*256 + kk*64 + kg*8);
            *(bf16x8*)(hlds + 32768 + m*128 + ((kg ^ (m & 7)) << 4)) = cvt8(px[0], px[1]);
        }
        __syncthreads();
        bf16x8 bp[2][4], xf[2][4];
        #pragma unroll
        for (int kb = 0; kb < 2; ++kb) {
            #pragma unroll
            for (int nt = 0; nt < 4; ++nt)
                bp[kb][nt] = __builtin_bit_cast(bf16x8,
                    Bpack[((kk*2 + kb)*16 + w*4 + nt)*64 + lane]);
            #pragma unroll
            for (int mt = 0; mt < 4; ++mt) {
                int m = mt*16 + r;
                xf[kb][mt] = *(const bf16x8*)(hlds + 32768 + m*128 +
                                              (((kb*4 + q) ^ (m & 7)) << 4));
            }
        }
        #pragma unroll
        for (int kb = 0; kb < 2; ++kb)
            #pragma unroll
            for (int nt = 0; nt < 4; ++nt)
                #pragma unroll
                for (int mt = 0; mt < 4; ++mt)
                    acc[nt][mt] = __builtin_amdgcn_mfma_f32_16x16x32_bf16(
                        bp[kb][nt], xf[kb][mt], acc[nt][mt], 0, 0, 0);
        __syncthreads();
    }
    // epilogue: lane holds 4 consecutive states (regs) -> one b64 per (nt,mt)
    #pragma unroll
    for (int nt = 0; nt < 4; ++nt) {
        int n0 = w*64 + nt*16 + q*4;
        #pragma unroll
        for (int mt = 0; mt < 4; ++mt) {
            int m = mt*16 + r;
            uint2 dd;
            dd.x = pack2(acc[nt][mt][0], acc[nt][mt][1]);
            dd.y = pack2(acc[nt][mt][2], acc[nt][mt][3]);
            *(uint2*)(hlds + m*512 + (((n0 >> 3) ^ ((m >> 1) & 31)) << 4) + (n0 & 7)*2) = dd;
        }
    }
    __syncthreads();

    // ---------------- phase 2: chunk-local scan ----------------
    int p = t & 127, ch = t >> 7;   // thread: states 2p,2p+1 ; chunk ch
    int cb = cbase + ch;
    float Ar0,Ai0,sr0,si0, Ar1,Ai1,sr1,si1;
    ssm_consts(llr, li, ldt, 2*p,   Ar0, Ai0, sr0, si0);
    ssm_consts(llr, li, ldt, 2*p+1, Ar1, Ai1, sr1, si1);
    {
        float hr0=0.f, hi0=0.f, hr1=0.f, hi1=0.f;
        #pragma unroll
        for (int i2 = 0; i2 < 16; ++i2) {
            int row = ch*32 + i2*2;
            char* a = hlds + row*512 + (((p >> 2) ^ ((row >> 1) & 31)) << 4) + (p & 3)*4;
            unsigned v0 = *(unsigned*)a;
            unsigned v1 = *(unsigned*)(a + 512);
            float x0 = b2f_lo(v0), x1 = b2f_hi(v0);
            float t0r = fmaf(Ar0, hr0, fmaf(-Ai0, hi0, sr0*x0));
            float t0i = fmaf(Ar0, hi0, fmaf( Ai0, hr0, si0*x0));
            float t1r = fmaf(Ar1, hr1, fmaf(-Ai1, hi1, sr1*x1));
            float t1i = fmaf(Ar1, hi1, fmaf( Ai1, hr1, si1*x1));
            hr0=t0r; hi0=t0i; hr1=t1r; hi1=t1i;
            *(unsigned*)a           = pack2(hr0, hr1);
            *(unsigned*)(a + 32768) = pack2(hi0, hi1);
            x0 = b2f_lo(v1); x1 = b2f_hi(v1);
            t0r = fmaf(Ar0, hr0, fmaf(-Ai0, hi0, sr0*x0));
            t0i = fmaf(Ar0, hi0, fmaf( Ai0, hr0, si0*x0));
            t1r = fmaf(Ar1, hr1, fmaf(-Ai1, hi1, sr1*x1));
            t1i = fmaf(Ar1, hi1, fmaf( Ai1, hr1, si1*x1));
            hr0=t0r; hi0=t0i; hr1=t1r; hi1=t1i;
            *(unsigned*)(a + 512)         = pack2(hr0, hr1);
            *(unsigned*)(a + 32768 + 512) = pack2(hi0, hi1);
        }
        // finals -> ws via relaxed agent-scope u64 atomics (write-through
        // to MALL; L2 holds no copy of these lines)
        float2 fr2; fr2.x = hr0; fr2.y = hr1;
        float2 fi2; fi2.x = hi0; fi2.y = hi1;
        size_t fidx = (size_t)(b*NCH + cb)*128 + p;
        __hip_atomic_store(finu + fidx, __builtin_bit_cast(u64_t, fr2),
                           __ATOMIC_RELAXED, __HIP_MEMORY_SCOPE_AGENT);
        __hip_atomic_store(finv + fidx, __builtin_bit_cast(u64_t, fi2),
                           __ATOMIC_RELAXED, __HIP_MEMORY_SCOPE_AGENT);
    }
    __syncthreads();   // drains vmcnt per wave -> all finals at MALL
    if (t == 0)
        __hip_atomic_store(flags + bid, 1, __ATOMIC_RELAXED, __HIP_MEMORY_SCOPE_AGENT);

    // ---------------- phase 3: wait (wave 0 only) + ONE fence/block ----------------
    if (d > 0) {                    // block-uniform
        if (w == 0) {
            int fi_ = b*64 + ((lane < d) ? lane : 0);
            while (true) {
                int fl = __hip_atomic_load(flags + fi_, __ATOMIC_RELAXED,
                                           __HIP_MEMORY_SCOPE_AGENT);
                if (__all(fl != 0)) break;
                __builtin_amdgcn_s_sleep(4);
            }
            __builtin_amdgcn_fence(__ATOMIC_ACQUIRE, "agent");  // one buffer_inv per BLOCK
        }
        __syncthreads();            // publishes the fence to all waves
    }
    if (cb > 0) {
        float P0r=Ar0, P0i=Ai0, P1r=Ar1, P1i=Ai1;   // -> A^32
        #pragma unroll
        for (int i = 0; i < 5; ++i) {
            float u0 = P0r*P0r - P0i*P0i; P0i = 2.f*P0r*P0i; P0r = u0;
            float u1 = P1r*P1r - P1i*P1i; P1i = 2.f*P1r*P1i; P1r = u1;
        }
        float c0r=0.f, c0i=0.f, c1r=0.f, c1i=0.f;
        // plain coalesced u64 loads (synced by the per-block fence; own-block
        // chunk finals are write-through so L2 holds no stale copy)
        #pragma unroll 4
        for (int j = 0; j < cb; ++j) {
            u64_t vr = finu[(size_t)(b*NCH + j)*128 + p];
            u64_t vi = finv[(size_t)(b*NCH + j)*128 + p];
            float2 fr = __builtin_bit_cast(float2, vr);
            float2 fi = __builtin_bit_cast(float2, vi);
            float n0r = fmaf(P0r, c0r, fmaf(-P0i, c0i, fr.x));
            float n0i = fmaf(P0r, c0i, fmaf( P0i, c0r, fi.x));
            float n1r = fmaf(P1r, c1r, fmaf(-P1i, c1i, fr.y));
            float n1i = fmaf(P1r, c1i, fmaf( P1i, c1r, fi.y));
            c0r=n0r; c0i=n0i; c1r=n1r; c1i=n1i;
        }
        float g0r = Ar0*c0r - Ai0*c0i, g0i = Ar0*c0i + Ai0*c0r;
        float g1r = Ar1*c1r - Ai1*c1i, g1i = Ar1*c1i + Ai1*c1r;
        #pragma unroll
        for (int i2 = 0; i2 < 16; ++i2) {
            int row = ch*32 + i2*2;
            char* a = hlds + row*512 + (((p >> 2) ^ ((row >> 1) & 31)) << 4) + (p & 3)*4;
            unsigned ur0 = *(unsigned*)a;
            unsigned ur1 = *(unsigned*)(a + 512);
            unsigned ui0 = *(unsigned*)(a + 32768);
            unsigned ui1 = *(unsigned*)(a + 32768 + 512);
            *(unsigned*)a           = pack2(b2f_lo(ur0) + g0r, b2f_hi(ur0) + g1r);
            *(unsigned*)(a + 32768) = pack2(b2f_lo(ui0) + g0i, b2f_hi(ui0) + g1i);
            { float t0 = Ar0*g0r - Ai0*g0i; g0i = fmaf(Ar0, g0i, Ai0*g0r); g0r = t0;
              float t1 = Ar1*g1r - Ai1*g1i; g1i = fmaf(Ar1, g1i, Ai1*g1r); g1r = t1; }
            *(unsigned*)(a + 512)         = pack2(b2f_lo(ur1) + g0r, b2f_hi(ur1) + g1r);
            *(unsigned*)(a + 32768 + 512) = pack2(b2f_lo(ui1) + g0i, b2f_hi(ui1) + g1i);
            { float t0 = Ar0*g0r - Ai0*g0i; g0i = fmaf(Ar0, g0i, Ai0*g0r); g0r = t0;
              float t1 = Ar1*g1r - Ai1*g1i; g1i = fmaf(Ar1, g1i, Ai1*g1r); g1r = t1; }
        }
    }
    __syncthreads();

    // ---------------- phase 4: out = [hr|hi] @ Cpack^T (K=512) ----------------
    f32x4 acc2[4][4] = {};  // [mt][nt]
    #pragma unroll
    for (int ks = 0; ks < 16; ++ks) {
        int base = (ks & 8) ? 32768 : 0;
        int kin = ks & 7;
        bf16x8 af[4];
        #pragma unroll
        for (int mt = 0; mt < 4; ++mt) {
            int row = mt*16 + r;
            af[mt] = *(const bf16x8*)(hlds + base + row*512 +
                     (((kin*4 + q) ^ ((row >> 1) & 31)) << 4));
        }
        #pragma unroll
        for (int nt = 0; nt < 4; ++nt) {
            bf16x8 cf = __builtin_bit_cast(bf16x8, Cpack[(ks*16 + w*4 + nt)*64 + lane]);
            #pragma unroll
            for (int mt = 0; mt < 4; ++mt)
                acc2[mt][nt] = __builtin_amdgcn_mfma_f32_16x16x32_bf16(
                    af[mt], cf, acc2[mt][nt], 0, 0, 0);
        }
    }
    #pragma unroll
    for (int mt = 0; mt < 4; ++mt)
        #pragma unroll
        for (int nt = 0; nt < 4; ++nt)
            #pragma unroll
            for (int reg = 0; reg < 4; ++reg)
                out[(size_t)(m0 + mt*16 + q*4 + reg)*NN + w*64 + nt*16 + r] =
                    acc2[mt][nt][reg];
}

extern "C" void kernel_launch(void* const* d_in, const int* in_sizes, int n_in,
                              void* d_out, int out_size, void* d_ws, size_t ws_size,
                              hipStream_t stream) {
    const float* x   = (const float*)d_in[0];
    const float* llr = (const float*)d_in[1];
    const float* li  = (const float*)d_in[2];
    const float* ldt = (const float*)d_in[3];
    const float* Bw  = (const float*)d_in[4];
    const float* Cr  = (const float*)d_in[5];
    const float* Ci  = (const float*)d_in[6];

    char* wsb = (char*)d_ws;
    u64_t* finu  = (u64_t*)(wsb + WS_FINU_B);
    u64_t* finv  = (u64_t*)(wsb + WS_FINV_B);
    int*   flags = (int*)(wsb + WS_FLAG_B);
    u32x4* Cpack = (u32x4*)(wsb + WS_CP_B);
    u32x4* Bpack = (u32x4*)(wsb + WS_BP_B);
    float* outp  = (float*)d_out;

    kprep<<<24, 256, 0, stream>>>(Bw, Cr, Ci, Cpack, Bpack, flags);
    kfused<<<512, 256, 0, stream>>>(x, llr, li, ldt, Bpack, Cpack,
                                    finu, finv, flags, outp);
}

// Round 9
// 125.864 us; speedup vs baseline: 1.1413x; 1.0162x over previous
//
#include <hip/hip_runtime.h>
#include <hip/hip_bf16.h>

// ---------- problem sizes (fixed by setup_inputs) ----------
#define BB 8
#define SS 4096
#define NN 256      // d_state = d_input = d_output
#define CHUNK 32
#define NCH (SS/CHUNK)  // 128 chunks per batch

// ---------- ws layout (bytes) ----------
#define WS_FINU_B ((size_t)0)                        // 1 MiB u64 (hr pairs)
#define WS_FINV_B ((size_t)1 << 20)                  // 1 MiB u64 (hi pairs)
#define WS_FLAG_B ((size_t)2 << 20)                  // 2 KiB int flags (512)
#define WS_CP_B   (((size_t)2 << 20) + 65536)        // Cpack 256 KB
#define WS_BP_B   (((size_t)2 << 20) + 65536 + 262144) // Bpack 128 KB

typedef __bf16 bf16_t;
typedef bf16_t bf16x8 __attribute__((ext_vector_type(8)));
typedef float  f32x4  __attribute__((ext_vector_type(4)));
typedef unsigned int u32x4 __attribute__((ext_vector_type(4)));
typedef unsigned long long u64_t;

__device__ inline bf16_t f2b(float f) {
    __hip_bfloat16 h = __float2bfloat16(f);
    return __builtin_bit_cast(bf16_t, h);
}
__device__ inline float b2f_lo(unsigned v) {
    unsigned u = v << 16; return __builtin_bit_cast(float, u);
}
__device__ inline float b2f_hi(unsigned v) {
    unsigned u = v & 0xffff0000u; return __builtin_bit_cast(float, u);
}
__device__ inline unsigned pack2(float lo, float hi) {
    unsigned a = (unsigned)__builtin_bit_cast(unsigned short, f2b(lo));
    unsigned b = (unsigned)__builtin_bit_cast(unsigned short, f2b(hi));
    return a | (b << 16);
}
__device__ inline bf16x8 cvt8(f32x4 a, f32x4 b) {
    bf16x8 o;
    o[0]=f2b(a[0]); o[1]=f2b(a[1]); o[2]=f2b(a[2]); o[3]=f2b(a[3]);
    o[4]=f2b(b[0]); o[5]=f2b(b[1]); o[6]=f2b(b[2]); o[7]=f2b(b[3]);
    return o;
}

// bilinear-discretization constants for state n (verified)
__device__ inline void ssm_consts(const float* llr, const float* li, const float* ldt,
                                  int n, float& Ar, float& Ai, float& sr, float& si) {
    float lr = -expf(llr[n]);
    float im = li[n];
    float dt = expf(ldt[n]);
    dt = fminf(fmaxf(dt, 0.005f), 0.1f);
    float hr = 0.5f * dt * lr, hi = 0.5f * dt * im;
    float dr = 1.f - hr, di = -hi;
    float inv = 1.f / (dr*dr + di*di);
    Ar = ((1.f + hr)*dr + hi*di) * inv;
    Ai = (hi*dr - (1.f + hr)*di) * inv;
    sr = dt * dr * inv;
    si = -dt * di * inv;
}

// ============================================================
// kprep: pack C (virtual K=512, [Cr | -Ci]) and B (K=256) into bf16
// MFMA fragment order (verified). bid 0..15 -> Cpack, 16..23 -> Bpack.
// bid 0 also clears the 512 flags (ws is re-poisoned every iteration).
// ============================================================
__global__ __launch_bounds__(256) void kprep(const float* __restrict__ Bw,
                                             const float* __restrict__ Cr,
                                             const float* __restrict__ Ci,
                                             u32x4* __restrict__ Cpack,
                                             u32x4* __restrict__ Bpack,
                                             int* __restrict__ flags) {
    int t = threadIdx.x, bid = blockIdx.x;
    if (bid == 0) {
        __hip_atomic_store(flags + t, 0, __ATOMIC_RELAXED, __HIP_MEMORY_SCOPE_AGENT);
        __hip_atomic_store(flags + t + 256, 0, __ATOMIC_RELAXED, __HIP_MEMORY_SCOPE_AGENT);
    }
    const float* src;
    float sign;
    u32x4* dst;
    int ks;
    if (bid < 16) { ks = bid;      src = (ks < 8) ? Cr : Ci; sign = (ks < 8) ? 1.f : -1.f; dst = Cpack; }
    else          { ks = bid - 16; src = Bw;                 sign = 1.f;                   dst = Bpack; }
    int ksl = ks & 7;
    #pragma unroll
    for (int jj = 0; jj < 4; ++jj) {
        int s = t + 256 * jj;
        int ot = s >> 6, lane = s & 63;
        int o  = ot*16 + (lane & 15);
        int kb = ksl*32 + (lane >> 4)*8;
        bf16x8 v;
        #pragma unroll
        for (int e = 0; e < 8; ++e) v[e] = f2b(sign * src[o*256 + kb + e]);
        dst[(ks*16 + ot)*64 + lane] = __builtin_bit_cast(u32x4, v);
    }
}

// Unified LDS addressing (hr at 0, hi at +32768):
//   byte(m, n) = m*512 + (((n>>3) ^ ((m>>1)&31)) << 4) + (n&7)*2
// X staging aliases the hi half:
//   byte(m, k) = 32768 + m*128 + (((k>>3) ^ (m&7)) << 4) + (k&7)*2

// ============================================================
// kfused (512 blocks x 256 thr, 2/CU => full co-residency):
//  ph1: V^T = Bpack @ X^T (swapped MFMA operands -> b64 epilogue)
//  ph2: chunk-local complex scan in LDS; finals -> ws (relaxed agent
//       write-through atomics), barrier, RELAXED per-block flag
//  ph3: WAVE-0-ONLY relaxed poll of <=63 predecessor flags, barrier,
//       then lookback via RELAXED AGENT ATOMIC u64 loads (coalesced
//       MALL-direct reads -- NO acquire fence, L2 never invalidated),
//       carry prefix + G-add in LDS
//  ph4: out = [hr|hi] @ Cpack^T (K=512) -- Cpack stays L2-warm
// Sync correctness WITHOUT fences: finals stores are write-through
// agent atomics; __syncthreads drains vmcnt (finals at MALL) before
// the flag store; consumer polls flag at MALL, barrier, then reads
// finals at MALL -- same coherence point, no L2 state involved.
// Deadlock-safe: waits only on smaller block IDs + all 512 blocks
// co-resident (2/CU x 256 CU, 64 KB LDS each).
// ============================================================
__global__ __launch_bounds__(256, 2) void kfused(
    const float* __restrict__ X,
    const float* __restrict__ llr,
    const float* __restrict__ li,
    const float* __restrict__ ldt,
    const u32x4* __restrict__ Bpack,
    const u32x4* __restrict__ Cpack,
    u64_t* __restrict__ finu,
    u64_t* __restrict__ finv,
    int* __restrict__ flags,
    float* __restrict__ out)
{
    __shared__ __align__(16) char hlds[65536];
    int t = threadIdx.x;
    int bid = blockIdx.x;
    int m0 = bid * 64;
    int b = bid >> 6;               // batch
    int d = bid & 63;               // block index within batch
    int cbase = d * 2;              // first chunk index of this block
    int w = t >> 6, lane = t & 63, q = lane >> 4, r = lane & 15;

    // ---------------- phase 1: V^T = Bw @ X^T ----------------
    f32x4 acc[4][4] = {};   // [nt][mt]: D rows = states, cols = m rows
    for (int kk = 0; kk < 4; ++kk) {
        #pragma unroll
        for (int ss = 0; ss < 2; ++ss) {
            int s = t + 256 * ss;
            int m = s >> 3, kg = s & 7;
            const f32x4* px = (const f32x4*)(X + (size_t)(m0 + m)*256 + kk*64 + kg*8);
            *(bf16x8*)(hlds + 32768 + m*128 + ((kg ^ (m & 7)) << 4)) = cvt8(px[0], px[1]);
        }
        __syncthreads();
        bf16x8 bp[2][4], xf[2][4];
        #pragma unroll
        for (int kb = 0; kb < 2; ++kb) {
            #pragma unroll
            for (int nt = 0; nt < 4; ++nt)
                bp[kb][nt] = __builtin_bit_cast(bf16x8,
                    Bpack[((kk*2 + kb)*16 + w*4 + nt)*64 + lane]);
            #pragma unroll
            for (int mt = 0; mt < 4; ++mt) {
                int m = mt*16 + r;
                xf[kb][mt] = *(const bf16x8*)(hlds + 32768 + m*128 +
                                              (((kb*4 + q) ^ (m & 7)) << 4));
            }
        }
        #pragma unroll
        for (int kb = 0; kb < 2; ++kb)
            #pragma unroll
            for (int nt = 0; nt < 4; ++nt)
                #pragma unroll
                for (int mt = 0; mt < 4; ++mt)
                    acc[nt][mt] = __builtin_amdgcn_mfma_f32_16x16x32_bf16(
                        bp[kb][nt], xf[kb][mt], acc[nt][mt], 0, 0, 0);
        __syncthreads();
    }
    // epilogue: lane holds 4 consecutive states (regs) -> one b64 per (nt,mt)
    #pragma unroll
    for (int nt = 0; nt < 4; ++nt) {
        int n0 = w*64 + nt*16 + q*4;
        #pragma unroll
        for (int mt = 0; mt < 4; ++mt) {
            int m = mt*16 + r;
            uint2 dd;
            dd.x = pack2(acc[nt][mt][0], acc[nt][mt][1]);
            dd.y = pack2(acc[nt][mt][2], acc[nt][mt][3]);
            *(uint2*)(hlds + m*512 + (((n0 >> 3) ^ ((m >> 1) & 31)) << 4) + (n0 & 7)*2) = dd;
        }
    }
    __syncthreads();

    // ---------------- phase 2: chunk-local scan ----------------
    int p = t & 127, ch = t >> 7;   // thread: states 2p,2p+1 ; chunk ch
    int cb = cbase + ch;
    float Ar0,Ai0,sr0,si0, Ar1,Ai1,sr1,si1;
    ssm_consts(llr, li, ldt, 2*p,   Ar0, Ai0, sr0, si0);
    ssm_consts(llr, li, ldt, 2*p+1, Ar1, Ai1, sr1, si1);
    {
        float hr0=0.f, hi0=0.f, hr1=0.f, hi1=0.f;
        #pragma unroll
        for (int i2 = 0; i2 < 16; ++i2) {
            int row = ch*32 + i2*2;
            char* a = hlds + row*512 + (((p >> 2) ^ ((row >> 1) & 31)) << 4) + (p & 3)*4;
            unsigned v0 = *(unsigned*)a;
            unsigned v1 = *(unsigned*)(a + 512);
            float x0 = b2f_lo(v0), x1 = b2f_hi(v0);
            float t0r = fmaf(Ar0, hr0, fmaf(-Ai0, hi0, sr0*x0));
            float t0i = fmaf(Ar0, hi0, fmaf( Ai0, hr0, si0*x0));
            float t1r = fmaf(Ar1, hr1, fmaf(-Ai1, hi1, sr1*x1));
            float t1i = fmaf(Ar1, hi1, fmaf( Ai1, hr1, si1*x1));
            hr0=t0r; hi0=t0i; hr1=t1r; hi1=t1i;
            *(unsigned*)a           = pack2(hr0, hr1);
            *(unsigned*)(a + 32768) = pack2(hi0, hi1);
            x0 = b2f_lo(v1); x1 = b2f_hi(v1);
            t0r = fmaf(Ar0, hr0, fmaf(-Ai0, hi0, sr0*x0));
            t0i = fmaf(Ar0, hi0, fmaf( Ai0, hr0, si0*x0));
            t1r = fmaf(Ar1, hr1, fmaf(-Ai1, hi1, sr1*x1));
            t1i = fmaf(Ar1, hi1, fmaf( Ai1, hr1, si1*x1));
            hr0=t0r; hi0=t0i; hr1=t1r; hi1=t1i;
            *(unsigned*)(a + 512)         = pack2(hr0, hr1);
            *(unsigned*)(a + 32768 + 512) = pack2(hi0, hi1);
        }
        // finals -> ws via relaxed agent-scope u64 atomics (write-through
        // to MALL; L2 holds no copy of these lines)
        float2 fr2; fr2.x = hr0; fr2.y = hr1;
        float2 fi2; fi2.x = hi0; fi2.y = hi1;
        size_t fidx = (size_t)(b*NCH + cb)*128 + p;
        __hip_atomic_store(finu + fidx, __builtin_bit_cast(u64_t, fr2),
                           __ATOMIC_RELAXED, __HIP_MEMORY_SCOPE_AGENT);
        __hip_atomic_store(finv + fidx, __builtin_bit_cast(u64_t, fi2),
                           __ATOMIC_RELAXED, __HIP_MEMORY_SCOPE_AGENT);
    }
    __syncthreads();   // drains vmcnt per wave -> all finals at MALL
    if (t == 0)
        __hip_atomic_store(flags + bid, 1, __ATOMIC_RELAXED, __HIP_MEMORY_SCOPE_AGENT);

    // ---------------- phase 3: wait (wave 0 only), NO fence ----------------
    if (d > 0) {                    // block-uniform
        if (w == 0) {
            int fi_ = b*64 + ((lane < d) ? lane : 0);
            while (true) {
                int fl = __hip_atomic_load(flags + fi_, __ATOMIC_RELAXED,
                                           __HIP_MEMORY_SCOPE_AGENT);
                if (__all(fl != 0)) break;
                __builtin_amdgcn_s_sleep(4);
            }
        }
        __syncthreads();            // all waves held until flags observed
    }
    if (cb > 0) {
        float P0r=Ar0, P0i=Ai0, P1r=Ar1, P1i=Ai1;   // -> A^32
        #pragma unroll
        for (int i = 0; i < 5; ++i) {
            float u0 = P0r*P0r - P0i*P0i; P0i = 2.f*P0r*P0i; P0r = u0;
            float u1 = P1r*P1r - P1i*P1i; P1i = 2.f*P1r*P1i; P1r = u1;
        }
        float c0r=0.f, c0i=0.f, c1r=0.f, c1i=0.f;
        // relaxed agent atomic u64 loads: coalesced MALL-direct reads
        // (just global_load_dwordx2 with L1/L2-bypass bits). No fence
        // needed -- producer and consumer share the MALL coherence point.
        #pragma unroll 4
        for (int j = 0; j < cb; ++j) {
            u64_t vr = __hip_atomic_load(finu + (size_t)(b*NCH + j)*128 + p,
                                         __ATOMIC_RELAXED, __HIP_MEMORY_SCOPE_AGENT);
            u64_t vi = __hip_atomic_load(finv + (size_t)(b*NCH + j)*128 + p,
                                         __ATOMIC_RELAXED, __HIP_MEMORY_SCOPE_AGENT);
            float2 fr = __builtin_bit_cast(float2, vr);
            float2 fi = __builtin_bit_cast(float2, vi);
            float n0r = fmaf(P0r, c0r, fmaf(-P0i, c0i, fr.x));
            float n0i = fmaf(P0r, c0i, fmaf( P0i, c0r, fi.x));
            float n1r = fmaf(P1r, c1r, fmaf(-P1i, c1i, fr.y));
            float n1i = fmaf(P1r, c1i, fmaf( P1i, c1r, fi.y));
            c0r=n0r; c0i=n0i; c1r=n1r; c1i=n1i;
        }
        float g0r = Ar0*c0r - Ai0*c0i, g0i = Ar0*c0i + Ai0*c0r;
        float g1r = Ar1*c1r - Ai1*c1i, g1i = Ar1*c1i + Ai1*c1r;
        #pragma unroll
        for (int i2 = 0; i2 < 16; ++i2) {
            int row = ch*32 + i2*2;
            char* a = hlds + row*512 + (((p >> 2) ^ ((row >> 1) & 31)) << 4) + (p & 3)*4;
            unsigned ur0 = *(unsigned*)a;
            unsigned ur1 = *(unsigned*)(a + 512);
            unsigned ui0 = *(unsigned*)(a + 32768);
            unsigned ui1 = *(unsigned*)(a + 32768 + 512);
            *(unsigned*)a           = pack2(b2f_lo(ur0) + g0r, b2f_hi(ur0) + g1r);
            *(unsigned*)(a + 32768) = pack2(b2f_lo(ui0) + g0i, b2f_hi(ui0) + g1i);
            { float t0 = Ar0*g0r - Ai0*g0i; g0i = fmaf(Ar0, g0i, Ai0*g0r); g0r = t0;
              float t1 = Ar1*g1r - Ai1*g1i; g1i = fmaf(Ar1, g1i, Ai1*g1r); g1r = t1; }
            *(unsigned*)(a + 512)         = pack2(b2f_lo(ur1) + g0r, b2f_hi(ur1) + g1r);
            *(unsigned*)(a + 32768 + 512) = pack2(b2f_lo(ui1) + g0i, b2f_hi(ui1) + g1i);
            { float t0 = Ar0*g0r - Ai0*g0i; g0i = fmaf(Ar0, g0i, Ai0*g0r); g0r = t0;
              float t1 = Ar1*g1r - Ai1*g1i; g1i = fmaf(Ar1, g1i, Ai1*g1r); g1r = t1; }
        }
    }
    __syncthreads();

    // ---------------- phase 4: out = [hr|hi] @ Cpack^T (K=512) ----------------
    f32x4 acc2[4][4] = {};  // [mt][nt]
    #pragma unroll
    for (int ks = 0; ks < 16; ++ks) {
        int base = (ks & 8) ? 32768 : 0;
        int kin = ks & 7;
        bf16x8 af[4];
        #pragma unroll
        for (int mt = 0; mt < 4; ++mt) {
            int row = mt*16 + r;
            af[mt] = *(const bf16x8*)(hlds + base + row*512 +
                     (((kin*4 + q) ^ ((row >> 1) & 31)) << 4));
        }
        #pragma unroll
        for (int nt = 0; nt < 4; ++nt) {
            bf16x8 cf = __builtin_bit_cast(bf16x8, Cpack[(ks*16 + w*4 + nt)*64 + lane]);
            #pragma unroll
            for (int mt = 0; mt < 4; ++mt)
                acc2[mt][nt] = __builtin_amdgcn_mfma_f32_16x16x32_bf16(
                    af[mt], cf, acc2[mt][nt], 0, 0, 0);
        }
    }
    #pragma unroll
    for (int mt = 0; mt < 4; ++mt)
        #pragma unroll
        for (int nt = 0; nt < 4; ++nt)
            #pragma unroll
            for (int reg = 0; reg < 4; ++reg)
                out[(size_t)(m0 + mt*16 + q*4 + reg)*NN + w*64 + nt*16 + r] =
                    acc2[mt][nt][reg];
}

extern "C" void kernel_launch(void* const* d_in, const int* in_sizes, int n_in,
                              void* d_out, int out_size, void* d_ws, size_t ws_size,
                              hipStream_t stream) {
    const float* x   = (const float*)d_in[0];
    const float* llr = (const float*)d_in[1];
    const float* li  = (const float*)d_in[2];
    const float* ldt = (const float*)d_in[3];
    const float* Bw  = (const float*)d_in[4];
    const float* Cr  = (const float*)d_in[5];
    const float* Ci  = (const float*)d_in[6];

    char* wsb = (char*)d_ws;
    u64_t* finu  = (u64_t*)(wsb + WS_FINU_B);
    u64_t* finv  = (u64_t*)(wsb + WS_FINV_B);
    int*   flags = (int*)(wsb + WS_FLAG_B);
    u32x4* Cpack = (u32x4*)(wsb + WS_CP_B);
    u32x4* Bpack = (u32x4*)(wsb + WS_BP_B);
    float* outp  = (float*)d_out;

    kprep<<<24, 256, 0, stream>>>(Bw, Cr, Ci, Cpack, Bpack, flags);
    kfused<<<512, 256, 0, stream>>>(x, llr, li, ldt, Bpack, Cpack,
                                    finu, finv, flags, outp);
}